// Round 7
// baseline (593.576 us; speedup 1.0000x reference)
//
#include <hip/hip_runtime.h>
#include <hip/hip_bf16.h>

// Problem dims (fixed): T=1024, B=32, DIN=256, H=256, AA=21, L=2
#define T_DIM 1024
#define B_DIM 32
#define DIN_DIM 256
#define H_DIM 256
#define AA_DIM 21
#define M_ROWS (B_DIM * T_DIM)   // 32768 rows, row index = b*T + t everywhere

typedef __attribute__((ext_vector_type(8))) short bf16x8;   // 8 bf16 = 4 VGPRs
typedef __attribute__((ext_vector_type(4))) float f32x4;

typedef __attribute__((address_space(3))) void lds_void;
typedef const __attribute__((address_space(1))) void glb_void;

#define LOG2E_F 1.44269504088896340736f

__device__ __forceinline__ void gload_lds16(const void* g, void* l) {
    // per-lane global gather -> LDS at (wave-uniform base + lane*16), async
    __builtin_amdgcn_global_load_lds((glb_void*)g, (lds_void*)l, 16, 0, 0);
}

__device__ __forceinline__ unsigned short f2bu(float f) {
    __hip_bfloat16 h = __float2bfloat16(f);
    unsigned short u;
    __builtin_memcpy(&u, &h, 2);
    return u;
}

// ---------------------------------------------------------------------------
// All weight/input converts fused into ONE dispatch (vectorized bulk paths).
#define CVT_V0 2097152            // 8388608 / 4
#define CVT_N1 524288
#define CVT_N2 1048576
#define CVT_V3 32768              // 131072 / 4
#define CVT_N4 8192
#define CVT_TOT (CVT_V0 + CVT_N1 + CVT_N2 + CVT_V3 + CVT_N4)
__global__ __launch_bounds__(256) void cvt_all(
    const float* __restrict__ x,  const float* __restrict__ w0,
    const float* __restrict__ w1, const float* __restrict__ fcw,
    const float* __restrict__ lpw,
    __hip_bfloat16* __restrict__ xb,  __hip_bfloat16* __restrict__ w0t,
    __hip_bfloat16* __restrict__ w1t, __hip_bfloat16* __restrict__ fcwb,
    __hip_bfloat16* __restrict__ lpwb)
{
    int i = blockIdx.x * 256 + threadIdx.x;
    if (i < CVT_V0) {
        float4 v = ((const float4*)x)[i];
        ushort4 o = { f2bu(v.x), f2bu(v.y), f2bu(v.z), f2bu(v.w) };
        ((ushort4*)xb)[i] = o;
        return;
    }
    i -= CVT_V0;
    if (i < CVT_N1) {   // w0t, K=256; input flat ((kk*2+dir)*4+k)*H + h
        int kk = i >> 11, rem = i & 2047;
        int dir = rem >> 10, k = (rem >> 8) & 3, h = rem & 255;
        w0t[(long)(dir * 1024 + h * 4 + k) * 256 + kk] = __float2bfloat16(w0[i]);
        return;
    }
    i -= CVT_N1;
    if (i < CVT_N2) {   // w1t, K=512
        int kk = i >> 11, rem = i & 2047;
        int dir = rem >> 10, k = (rem >> 8) & 3, h = rem & 255;
        w1t[(long)(dir * 1024 + h * 4 + k) * 512 + kk] = __float2bfloat16(w1[i]);
        return;
    }
    i -= CVT_N2;
    if (i < CVT_V3) {
        float4 v = ((const float4*)fcw)[i];
        ushort4 o = { f2bu(v.x), f2bu(v.y), f2bu(v.z), f2bu(v.w) };
        ((ushort4*)fcwb)[i] = o;
        return;
    }
    i -= CVT_V3;
    if (i < CVT_N4) {   // lpwb (32,256), zero-padded past row 20
        int n = i >> 8, k = i & 255;
        lpwb[i] = __float2bfloat16(n < AA_DIM ? lpw[n * 256 + k] : 0.0f);
    }
}

#define MFMA16(d, a, b) d = __builtin_amdgcn_mfma_f32_16x16x32_bf16(a, b, d, 0, 0, 0)

// ---------------------------------------------------------------------------
// 256x256-tile 8-wave U-GEMM, A GLOBAL->REGISTER (no LDS for A), B in LDS.
// Rationale (r6 counters): prior all-LDS structure was LDS-port-bound:
// per K-tile LDS cyc ~2300 vs MFMA-pipe 621 -> MfmaUtil 27% == 621/2300.
// A rows have no cross-block reuse -> direct global->reg fragments (pattern
// refcheck-proven in the r3 fused kernel); A-dup (2x, wave decomp 4x2) hits
// L1 (per-K-tile A slice = 32 KiB = L1 size). B stays in LDS via the proven
// swizzled gload_lds staging. Counted vmcnt(12) = 8 A-loads + 4 B-stages of
// the kt+2 group in flight; never drains mid-loop. 2 barriers per K-tile.
// U2 output epilogue carried verbatim.
__global__ __launch_bounds__(512, 1) void gemm256_areg(
    const __hip_bfloat16* __restrict__ A,
    const __hip_bfloat16* __restrict__ Bt,
    __hip_bfloat16* __restrict__ C,
    int K, int nbShift)
{
    __shared__ __align__(16) char smb[69632];   // B dbuf 2x32K; epi scratch 67.5K

    const int tid  = threadIdx.x;
    const int lane = tid & 63;
    const int wave = tid >> 6;    // 0..7
    const int wm   = wave >> 1;   // 0..3  (64-row band)
    const int wn   = wave & 1;    // 0..1  (128-col band)

    const int L  = blockIdx.x;
    const int s  = L >> 3;
    const int nb = s & ((1 << nbShift) - 1);
    const int mb = ((s >> nbShift) << 3) + (L & 7);
    const long n0 = (long)nb * 256;
    const long m0 = (long)mb * 256;

    // B staging swizzle (proven: 0 conflicts vs the frag-read side)
    const int ldrow = lane >> 2;
    const int ldq   = lane & 3;
    const int gq    = ldq ^ ((ldrow >> 1) & 3);
    const int gkoff = gq * 8;

    // fragment coords
    const int fr = lane & 15;
    const int kq = lane >> 4;
    const int sw = (kq ^ ((fr >> 1) & 3)) * 16;

    const long arow = m0 + wm * 64 + fr;      // + mf*16
    f32x4 acc[4][8] = {};
    bf16x8 ar[2][8];
    const int NT = K >> 6;

    // B stage: 32 KiB per K-tile, 4 gload_lds per thread (cid = wave*4+i)
#define STAGE_B(BUF, KB)                                                    \
    do {                                                                    \
        _Pragma("unroll")                                                   \
        for (int i2 = 0; i2 < 4; ++i2) {                                    \
            const int cid = wave * 4 + i2;                                  \
            const int rc  = cid >> 1;                                       \
            const int kh  = cid & 1;                                        \
            gload_lds16(Bt + (n0 + rc * 16 + ldrow) * (long)K +             \
                            (KB) + kh * 32 + gkoff,                         \
                        (BUF) + rc * 2048 + kh * 1024);                     \
        }                                                                   \
    } while (0)

    // A frags: 8 b128 global loads per K-tile (4 mf x 2 kh)
#define LOAD_A(DST, KB)                                                     \
    do {                                                                    \
        _Pragma("unroll")                                                   \
        for (int mf = 0; mf < 4; ++mf)                                      \
            _Pragma("unroll")                                               \
            for (int kh = 0; kh < 2; ++kh)                                  \
                (DST)[mf * 2 + kh] = *(const bf16x8*)(A +                   \
                    (arow + mf * 16) * (long)K + (KB) + kh * 32 + kq * 8);  \
    } while (0)

    // prologue: tiles 0 and 1; tile1's 12 ops stay in flight
    LOAD_A(ar[0], 0);
    STAGE_B(smb, 0);
    __builtin_amdgcn_sched_barrier(0);
    LOAD_A(ar[1], 64);
    STAGE_B(smb + 32768, 64);
    asm volatile("s_waitcnt vmcnt(12)" ::: "memory");
    __builtin_amdgcn_s_barrier();

    for (int kt = 0; kt < NT; ++kt) {
        const char* bb = smb + (kt & 1) * 32768;
        const int par = kt & 1;

        __builtin_amdgcn_s_setprio(1);
#pragma unroll
        for (int kh = 0; kh < 2; ++kh) {
#pragma unroll
            for (int nfh = 0; nfh < 2; ++nfh) {
                bf16x8 bf[4];
#pragma unroll
                for (int q = 0; q < 4; ++q)
                    bf[q] = *(const bf16x8*)(bb + (wn * 8 + nfh * 4 + q) * 2048 +
                                             kh * 1024 + fr * 64 + sw);
#pragma unroll
                for (int mf = 0; mf < 4; ++mf)
#pragma unroll
                    for (int q = 0; q < 4; ++q)
                        MFMA16(acc[mf][nfh * 4 + q], ar[par][mf * 2 + kh], bf[q]);
            }
        }
        __builtin_amdgcn_s_setprio(0);
        __builtin_amdgcn_s_barrier();       // all waves done with buf/ar[par]

        __builtin_amdgcn_sched_barrier(0);
        if (kt + 2 < NT) {
            LOAD_A(ar[par], (kt + 2) * 64);
            STAGE_B((char*)bb, (kt + 2) * 64);
            __builtin_amdgcn_sched_barrier(0);
            asm volatile("s_waitcnt vmcnt(12)" ::: "memory"); // kt+1 done
        } else if (kt + 1 < NT) {
            asm volatile("s_waitcnt vmcnt(0)" ::: "memory");  // final drain
        }
        __builtin_amdgcn_s_barrier();       // kt+1 data ready for all waves
    }
#undef STAGE_B
#undef LOAD_A

    // ---- epilogue: 2 passes of 128 rows via LDS (stride 264 bf16), U2 out ----
    // C/D layout: col=lane&15, row=(lane>>4)*4+reg
    const int col_l = lane & 15;
    const int row_l = (lane >> 4) * 4;
    __hip_bfloat16* smC = (__hip_bfloat16*)smb;
    const int chunk = tid & 31;          // 8-col chunk
    const int rbase = tid >> 5;          // 0..15
#pragma unroll
    for (int p = 0; p < 2; ++p) {
        __syncthreads();
        if ((wm >> 1) == p) {
#pragma unroll
            for (int mf = 0; mf < 4; ++mf)
#pragma unroll
                for (int nf = 0; nf < 8; ++nf)
#pragma unroll
                    for (int r = 0; r < 4; ++r)
                        smC[((wm & 1) * 64 + mf * 16 + row_l + r) * 264 +
                            wn * 128 + nf * 16 + col_l] =
                            __float2bfloat16(acc[mf][nf][r]);
        }
        __syncthreads();
#pragma unroll
        for (int it = 0; it < 8; ++it) {
            const int rr = it * 16 + rbase;
            bf16x8 v = *(const bf16x8*)(smC + rr * 264 + chunk * 8);
            const long gr  = m0 + p * 128 + rr;
            const long gc0 = n0 + chunk * 8;
            const int bI  = (int)(gr >> 10);
            const int t   = (int)(gr & 1023);
            const int dir = (int)(gc0 >> 10);
            const int hg  = ((int)gc0 >> 8) & 3;
            const int beta = bI * 8 + dir * 4 + hg;
            const long base = ((long)beta * 1024 + t) * 256 + ((int)gc0 & 255);
            *(bf16x8*)(C + base) = v;     // one tile row = contiguous 512B in U2
        }
    }
}

// ---------------------------------------------------------------------------
// SRU scan, producer-consumer (round-2 harness-verified kernel).
#define SCAN_S 64
#define SCAN_NB (T_DIM / SCAN_S)   // 16
#define GRP 16

__device__ __forceinline__ float scan_step(
    uint2 u, float c, float nvf, float nvr, float nbf, float nbr,
    __hip_bfloat16* hq)
{
    float u0, u1, u2, u3;
    unsigned a0 = u.x << 16, a1 = u.x & 0xffff0000u;
    unsigned a2 = u.y << 16, a3 = u.y & 0xffff0000u;
    __builtin_memcpy(&u0, &a0, 4); __builtin_memcpy(&u1, &a1, 4);
    __builtin_memcpy(&u2, &a2, 4); __builtin_memcpy(&u3, &a3, 4);
    const float nf0 = __builtin_fmaf(-LOG2E_F, u1, nbf);
    const float nr0 = __builtin_fmaf(-LOG2E_F, u2, nbr);
    const float ef = __builtin_amdgcn_exp2f(__builtin_fmaf(nvf, c, nf0));
    const float er = __builtin_amdgcn_exp2f(__builtin_fmaf(nvr, c, nr0));
    const float f  = __builtin_amdgcn_rcpf(1.0f + ef);
    const float r  = __builtin_amdgcn_rcpf(1.0f + er);
    const float c2 = __builtin_fmaf(f, c - u0, u0);
    const float hv = __builtin_fmaf(r, c2 - u3, u3);
    *hq = __float2bfloat16(hv);
    return c2;
}

__global__ __launch_bounds__(256) void sru_scan(
    const __hip_bfloat16* __restrict__ U2,
    const float* __restrict__ wc,    // (2,2,H)
    const float* __restrict__ bias,  // (2,2,H)
    __hip_bfloat16* __restrict__ hout)
{
    __shared__ __align__(16) char lds[2 * SCAN_S * 512];   // 65536 B
    const int tid  = threadIdx.x;
    const int wave = tid >> 6;
    const int lane = tid & 63;
    const int beta = blockIdx.x;
    const int b    = beta >> 3;
    const int dir  = (beta >> 2) & 1;
    const int hg   = beta & 3;
    const int h    = hg * 64 + lane;

    const char* gslice = (const char*)U2 + (size_t)beta * (1024 * 512);

    const float nvf = -LOG2E_F * wc[(dir * 2 + 0) * H_DIM + h];
    const float nvr = -LOG2E_F * wc[(dir * 2 + 1) * H_DIM + h];
    const float nbf = -LOG2E_F * bias[(dir * 2 + 0) * H_DIM + h];
    const float nbr = -LOG2E_F * bias[(dir * 2 + 1) * H_DIM + h];
    __hip_bfloat16* hp = hout + ((long)(b * 1024 + (dir ? 1023 : 0))) * 512 + dir * 256 + h;
    const long hstep = dir ? -512L : 512L;
    float c = 0.0f;

    const int plane = lane & 31;

    if (wave > 0) {
        for (int p = wave - 1; p < SCAN_S / 2; p += 3) {
            const int sl = 2 * p + (lane >> 5);
            const int t  = dir ? (1023 - sl) : sl;
            gload_lds16(gslice + (size_t)t * 512 + plane * 16, lds + p * 1024);
        }
    }
    __syncthreads();

    for (int bat = 0; bat < SCAN_NB; ++bat) {
        if (wave > 0) {
            if (bat + 1 < SCAN_NB) {
                char* halfN = lds + ((bat + 1) & 1) * (SCAN_S * 512);
                const int tb = (bat + 1) * SCAN_S;
                for (int p = wave - 1; p < SCAN_S / 2; p += 3) {
                    const int sl = tb + 2 * p + (lane >> 5);
                    const int t  = dir ? (1023 - sl) : sl;
                    gload_lds16(gslice + (size_t)t * 512 + plane * 16,
                                halfN + p * 1024);
                }
            }
        } else {
            const char* half = lds + (bat & 1) * (SCAN_S * 512);
            __hip_bfloat16* hq = hp + (long)(bat * SCAN_S) * hstep;
            uint2 qa[GRP], qb[GRP];
#pragma unroll
            for (int j = 0; j < GRP; ++j)
                qa[j] = *(const uint2*)(half + (0 * GRP + j) * 512 + (lane << 3));
#pragma unroll
            for (int j = 0; j < GRP; ++j)
                qb[j] = *(const uint2*)(half + (1 * GRP + j) * 512 + (lane << 3));
#pragma unroll
            for (int j = 0; j < GRP; ++j)
                c = scan_step(qa[j], c, nvf, nvr, nbf, nbr, hq + (long)j * hstep);
#pragma unroll
            for (int j = 0; j < GRP; ++j)
                qa[j] = *(const uint2*)(half + (2 * GRP + j) * 512 + (lane << 3));
#pragma unroll
            for (int j = 0; j < GRP; ++j)
                c = scan_step(qb[j], c, nvf, nvr, nbf, nbr, hq + (long)(GRP + j) * hstep);
#pragma unroll
            for (int j = 0; j < GRP; ++j)
                qb[j] = *(const uint2*)(half + (3 * GRP + j) * 512 + (lane << 3));
#pragma unroll
            for (int j = 0; j < GRP; ++j)
                c = scan_step(qa[j], c, nvf, nvr, nbf, nbr, hq + (long)(2 * GRP + j) * hstep);
#pragma unroll
            for (int j = 0; j < GRP; ++j)
                c = scan_step(qb[j], c, nvf, nvr, nbf, nbr, hq + (long)(3 * GRP + j) * hstep);
        }
        __syncthreads();
    }
}

// ---------------------------------------------------------------------------
// FUSED fc GEMM + logits + log_softmax (round-6 harness-verified kernel).
#define FL_BUF 49152             // per-kt staging: A 16384 + B 32768
#define FL_LP  98304             // lpwb region: 32 x 528 = 16896
#define FL_SCR 115200            // logits scratch: 128 x 36 f32 = 18432
#define FL_TOT 133632

__global__ __launch_bounds__(512, 1) void fc_logits(
    const __hip_bfloat16* __restrict__ A,     // h1b (32768, 512)
    const __hip_bfloat16* __restrict__ Bw,    // fc1wb (256, 512)
    const float* __restrict__ fcb,            // fc1_b (256,)
    const __hip_bfloat16* __restrict__ lpwb,  // (32,256) bf16, padded
    const float* __restrict__ lpb,            // (21,)
    float* __restrict__ out)                  // (32768, 21) f32
{
    __shared__ __align__(16) char lds[FL_TOT];
    const int tid  = threadIdx.x;
    const int lane = tid & 63;
    const int wave = tid >> 6;    // 0..7
    const int wm   = wave & 1;    // row half (64)
    const int wn   = wave >> 1;   // col quarter (64)
    const long m0  = (long)blockIdx.x * 128;

    const int ldrow = lane >> 2;
    const int ldq   = lane & 3;
    const int gq    = ldq ^ ((ldrow >> 1) & 3);
    const int gkoff = gq * 8;

    const int fr = lane & 15;
    const int kq = lane >> 4;
    const int sw = (kq ^ ((fr >> 1) & 3)) * 16;

    // stage lpwb (16 KB) once at 528-stride (vector loads + ds writes)
    for (int idx = tid; idx < 1024; idx += 512) {
        const int rw = idx >> 5, sl = idx & 31;
        *(bf16x8*)(lds + FL_LP + rw * 528 + sl * 16) =
            *(const bf16x8*)(lpwb + rw * 256 + sl * 8);
    }
    __builtin_amdgcn_sched_barrier(0);

    // ---- phase 1: fc GEMM, K=512, NT=8, dbuf, counted vmcnt(6) ----
    f32x4 acc[4][4] = {};

#define STAGE_FL(BUF, KB)                                                   \
    do {                                                                    \
        _Pragma("unroll")                                                   \
        for (int i2 = 0; i2 < 6; ++i2) {                                    \
            const int sg = wave * 6 + i2;  /* 0..47 */                      \
            if (sg < 16) {         /* A: 8 rc x 2 kh */                     \
                const int rc = sg >> 1, kh = sg & 1;                        \
                gload_lds16(A + (m0 + rc * 16 + ldrow) * 512L +             \
                                (KB) + kh * 32 + gkoff,                     \
                            (BUF) + rc * 2048 + kh * 1024);                 \
            } else {               /* B: 16 rc x 2 kh */                    \
                const int t2 = sg - 16, rc = t2 >> 1, kh = t2 & 1;          \
                gload_lds16(Bw + (rc * 16 + ldrow) * 512L +                 \
                                 (KB) + kh * 32 + gkoff,                    \
                            (BUF) + 16384 + rc * 2048 + kh * 1024);         \
            }                                                               \
        }                                                                   \
    } while (0)

    STAGE_FL(lds, 0);

    for (int kt = 0; kt < 8; ++kt) {
        char* cur = lds + (kt & 1) * FL_BUF;
        char* nxt = lds + ((kt + 1) & 1) * FL_BUF;
        __builtin_amdgcn_sched_barrier(0);
        if (kt + 1 < 8) {
            STAGE_FL(nxt, (kt + 1) * 64);
            __builtin_amdgcn_sched_barrier(0);
            asm volatile("s_waitcnt vmcnt(6)" ::: "memory");
        } else {
            asm volatile("s_waitcnt vmcnt(0)" ::: "memory");
        }
        __builtin_amdgcn_s_barrier();

#pragma unroll
        for (int ss = 0; ss < 2; ++ss) {
            bf16x8 af[4], bfv[4];
#pragma unroll
            for (int i = 0; i < 4; ++i) {
                af[i]  = *(const bf16x8*)(cur + (wm * 4 + i) * 2048 + ss * 1024 + fr * 64 + sw);
                bfv[i] = *(const bf16x8*)(cur + 16384 + (wn * 4 + i) * 2048 + ss * 1024 + fr * 64 + sw);
            }
            __builtin_amdgcn_s_setprio(1);
#pragma unroll
            for (int i = 0; i < 4; ++i)
#pragma unroll
                for (int j = 0; j < 4; ++j)
                    MFMA16(acc[i][j], af[i], bfv[j]);
            __builtin_amdgcn_s_setprio(0);
        }
        __builtin_amdgcn_s_barrier();   // reads of cur complete
    }
#undef STAGE_FL

    // ---- dump fc tile to LDS as bf16, stride 260 elems (+bias) ----
    const int col_l = lane & 15;
    const int row_l = (lane >> 4) * 4;
    __hip_bfloat16* fcX = (__hip_bfloat16*)lds;
#pragma unroll
    for (int j = 0; j < 4; ++j) {
        const int gc = wn * 64 + j * 16 + col_l;
        const float bv = fcb[gc];
#pragma unroll
        for (int i = 0; i < 4; ++i)
#pragma unroll
            for (int r = 0; r < 4; ++r)
                fcX[(wm * 64 + i * 16 + row_l + r) * 260 + gc] =
                    __float2bfloat16(acc[i][j][r] + bv);
    }
    __syncthreads();

    // ---- phase 2: logits MFMA over K=256 from LDS ----
    const int rb = wave * 16;     // 16 rows per wave
    f32x4 acc2[2] = {};
#pragma unroll
    for (int kc = 0; kc < 8; ++kc) {
        bf16x8 afx = *(const bf16x8*)(lds + (rb + fr) * 520 + kc * 64 + kq * 16);
        bf16x8 b0  = *(const bf16x8*)(lds + FL_LP + fr * 528 + kc * 64 + kq * 16);
        bf16x8 b1  = *(const bf16x8*)(lds + FL_LP + (16 + fr) * 528 + kc * 64 + kq * 16);
        MFMA16(acc2[0], afx, b0);
        MFMA16(acc2[1], afx, b1);
    }

    float* smL = (float*)(lds + FL_SCR);   // stride 36 f32
#pragma unroll
    for (int j = 0; j < 2; ++j) {
        const int gc = j * 16 + col_l;
        const float bv = (gc < AA_DIM) ? lpb[gc] : 0.0f;
#pragma unroll
        for (int r = 0; r < 4; ++r)
            smL[(rb + row_l + r) * 36 + gc] = acc2[j][r] + bv;
    }
    __syncthreads();

    if (tid < 128) {
        const float* rowp = smL + tid * 36;
        float m = rowp[0];
#pragma unroll
        for (int a = 1; a < AA_DIM; ++a) m = fmaxf(m, rowp[a]);
        float s = 0.0f;
#pragma unroll
        for (int a = 0; a < AA_DIM; ++a) s += __expf(rowp[a] - m);
        const float lse = __logf(s) + m;
        float* op = out + (m0 + tid) * AA_DIM;
#pragma unroll
        for (int a = 0; a < AA_DIM; ++a) op[a] = rowp[a] - lse;
    }
}

// ---------------------------------------------------------------------------
extern "C" void kernel_launch(void* const* d_in, const int* in_sizes, int n_in,
                              void* d_out, int out_size, void* d_ws, size_t ws_size,
                              hipStream_t stream)
{
    const float* x     = (const float*)d_in[0];
    const float* w_l0  = (const float*)d_in[2];
    const float* wc_l0 = (const float*)d_in[3];
    const float* b_l0  = (const float*)d_in[4];
    const float* w_l1  = (const float*)d_in[5];
    const float* wc_l1 = (const float*)d_in[6];
    const float* b_l1  = (const float*)d_in[7];
    const float* fc1_w = (const float*)d_in[8];
    const float* fc1_b = (const float*)d_in[9];
    const float* lp_w  = (const float*)d_in[10];
    const float* lp_b  = (const float*)d_in[11];
    float* out = (float*)d_out;

    char* ws = (char*)d_ws;
    __hip_bfloat16* U      = (__hip_bfloat16*)(ws);              // 134,217,728 B (U2 layout)
    __hip_bfloat16* h0b    = (__hip_bfloat16*)(ws + 134217728);  //  33,554,432
    __hip_bfloat16* h1b    = (__hip_bfloat16*)(ws + 167772160);  //  33,554,432
    __hip_bfloat16* xb     = (__hip_bfloat16*)(ws + 201326592);  //  16,777,216
    __hip_bfloat16* w0t    = (__hip_bfloat16*)(ws + 218103808);  //  (2048,256)
    __hip_bfloat16* w1t    = (__hip_bfloat16*)(ws + 219152384);  //  (2048,512)
    __hip_bfloat16* fc1wb  = (__hip_bfloat16*)(ws + 221249536);  //  (256,512)
    __hip_bfloat16* lpwb   = (__hip_bfloat16*)(ws + 221511680);  //  (32,256)

    cvt_all<<<(CVT_TOT + 255) / 256, 256, 0, stream>>>(
        x, w_l0, w_l1, fc1_w, lp_w, xb, w0t, w1t, fc1wb, lpwb);

    // U-GEMMs: 256^2 tiles, A-from-global, MB=128 x NB=8 -> 1024 blocks
    gemm256_areg<<<1024, 512, 0, stream>>>(xb, w0t, U, DIN_DIM, 3);
    sru_scan<<<256, 256, 0, stream>>>(U, wc_l0, b_l0, h0b);
    gemm256_areg<<<1024, 512, 0, stream>>>(h0b, w1t, U, 512, 3);
    sru_scan<<<256, 256, 0, stream>>>(U, wc_l1, b_l1, h1b);

    // fused fc GEMM + logits + log_softmax: 256 blocks (1/CU), 8 waves
    fc_logits<<<256, 512, 0, stream>>>(h1b, fc1wb, fc1_b, lpwb, lp_b, out);
}

// Round 9
// 378.599 us; speedup vs baseline: 1.5678x; 1.5678x over previous
//
#include <hip/hip_runtime.h>
#include <hip/hip_bf16.h>

// Problem dims (fixed): T=1024, B=32, DIN=256, H=256, AA=21, L=2
#define T_DIM 1024
#define B_DIM 32
#define DIN_DIM 256
#define H_DIM 256
#define AA_DIM 21
#define M_ROWS (B_DIM * T_DIM)   // 32768 rows, row index = b*T + t everywhere

typedef __attribute__((ext_vector_type(8))) short bf16x8;   // 8 bf16 = 4 VGPRs
typedef __attribute__((ext_vector_type(4))) float f32x4;

typedef __attribute__((address_space(3))) void lds_void;
typedef const __attribute__((address_space(1))) void glb_void;

#define LOG2E_F 1.44269504088896340736f

__device__ __forceinline__ void gload_lds16(const void* g, void* l) {
    // per-lane global gather -> LDS at (wave-uniform base + lane*16), async
    __builtin_amdgcn_global_load_lds((glb_void*)g, (lds_void*)l, 16, 0, 0);
}

__device__ __forceinline__ unsigned short f2bu(float f) {
    __hip_bfloat16 h = __float2bfloat16(f);
    unsigned short u;
    __builtin_memcpy(&u, &h, 2);
    return u;
}

// ---------------------------------------------------------------------------
// All weight/input converts fused into ONE dispatch (vectorized bulk paths).
#define CVT_V0 2097152            // 8388608 / 4
#define CVT_N1 524288
#define CVT_N2 1048576
#define CVT_V3 32768              // 131072 / 4
#define CVT_N4 8192
#define CVT_TOT (CVT_V0 + CVT_N1 + CVT_N2 + CVT_V3 + CVT_N4)
__global__ __launch_bounds__(256) void cvt_all(
    const float* __restrict__ x,  const float* __restrict__ w0,
    const float* __restrict__ w1, const float* __restrict__ fcw,
    const float* __restrict__ lpw,
    __hip_bfloat16* __restrict__ xb,  __hip_bfloat16* __restrict__ w0t,
    __hip_bfloat16* __restrict__ w1t, __hip_bfloat16* __restrict__ fcwb,
    __hip_bfloat16* __restrict__ lpwb)
{
    int i = blockIdx.x * 256 + threadIdx.x;
    if (i < CVT_V0) {
        float4 v = ((const float4*)x)[i];
        ushort4 o = { f2bu(v.x), f2bu(v.y), f2bu(v.z), f2bu(v.w) };
        ((ushort4*)xb)[i] = o;
        return;
    }
    i -= CVT_V0;
    if (i < CVT_N1) {   // w0t, K=256; input flat ((kk*2+dir)*4+k)*H + h
        int kk = i >> 11, rem = i & 2047;
        int dir = rem >> 10, k = (rem >> 8) & 3, h = rem & 255;
        w0t[(long)(dir * 1024 + h * 4 + k) * 256 + kk] = __float2bfloat16(w0[i]);
        return;
    }
    i -= CVT_N1;
    if (i < CVT_N2) {   // w1t, K=512
        int kk = i >> 11, rem = i & 2047;
        int dir = rem >> 10, k = (rem >> 8) & 3, h = rem & 255;
        w1t[(long)(dir * 1024 + h * 4 + k) * 512 + kk] = __float2bfloat16(w1[i]);
        return;
    }
    i -= CVT_N2;
    if (i < CVT_V3) {
        float4 v = ((const float4*)fcw)[i];
        ushort4 o = { f2bu(v.x), f2bu(v.y), f2bu(v.z), f2bu(v.w) };
        ((ushort4*)fcwb)[i] = o;
        return;
    }
    i -= CVT_V3;
    if (i < CVT_N4) {   // lpwb (32,256), zero-padded past row 20
        int n = i >> 8, k = i & 255;
        lpwb[i] = __float2bfloat16(n < AA_DIM ? lpw[n * 256 + k] : 0.0f);
    }
}

#define MFMA16(d, a, b) d = __builtin_amdgcn_mfma_f32_16x16x32_bf16(a, b, d, 0, 0, 0)

// ---------------------------------------------------------------------------
// 256x256-tile 8-wave GEMM (4-phase schedule, counted vmcnt, T5 setprio) for
// the two U-GEMMs: C = A*Bt^T written in the scan-friendly U2 layout
// [beta=b*8+dir*4+hg][t][64h x 4k]. BK=64, double-buffered 128 KiB LDS.
// (Round-2/6 harness-verified kernel, ~102 us/dispatch. Known structural
// ceiling: all-LDS decomposition reads 192 KiB LDS per K-tile vs 621 cyc of
// MFMA -> MfmaUtil ~27%. A-in-register variants failed verification twice
// (r7 scratch spill; r8 unexplained miscompare) -> arc suspended.)
__device__ __forceinline__ void stage_tile256(
    const __hip_bfloat16* __restrict__ A,
    const __hip_bfloat16* __restrict__ Bt,
    char* buf, long m0, long n0, int K, int kb,
    int wave, int ldrow, int gkoff)
{
#pragma unroll
    for (int i = 0; i < 4; ++i) {
        const int cid = wave * 4 + i;      // 0..31
        const int rc  = cid >> 1;          // 16-row granule, 0..15
        const int kh  = cid & 1;           // which 32-k half of BK=64
        const long row = rc * 16 + ldrow;
        const int koff = kb + kh * 32 + gkoff;
        gload_lds16(A  + (m0 + row) * (long)K + koff,
                    buf + rc * 2048 + kh * 1024);
        gload_lds16(Bt + (n0 + row) * (long)K + koff,
                    buf + 32768 + rc * 2048 + kh * 1024);
    }
}

__global__ __launch_bounds__(512, 2) void gemm256_u2(
    const __hip_bfloat16* __restrict__ A,
    const __hip_bfloat16* __restrict__ Bt,
    __hip_bfloat16* __restrict__ C,
    int K, int nbShift)
{
    __shared__ __align__(16) char smb[131072];   // 2 x (A 32K + B 32K)

    const int tid  = threadIdx.x;
    const int lane = tid & 63;
    const int wave = tid >> 6;    // 0..7
    const int wm   = wave >> 2;   // 0..1  (128-row half)
    const int wn   = wave & 3;    // 0..3  (64-col quarter)

    const int L  = blockIdx.x;
    const int s  = L >> 3;
    const int nb = s & ((1 << nbShift) - 1);
    const int mb = ((s >> nbShift) << 3) + (L & 7);
    const long n0 = (long)nb * 256;
    const long m0 = (long)mb * 256;

    const int ldrow = lane >> 2;
    const int ldq   = lane & 3;
    const int gq    = ldq ^ ((ldrow >> 1) & 3);
    const int gkoff = gq * 8;

    const int fr = lane & 15;
    const int kq = lane >> 4;
    const int sw = (kq ^ ((fr >> 1) & 3)) * 16;

    f32x4 acc[8][4] = {};
    const int NT = K >> 6;

    stage_tile256(A, Bt, smb,         m0, n0, K, 0,  wave, ldrow, gkoff);
    __builtin_amdgcn_sched_barrier(0);
    stage_tile256(A, Bt, smb + 65536, m0, n0, K, 64, wave, ldrow, gkoff);
    asm volatile("s_waitcnt vmcnt(8)" ::: "memory");
    __builtin_amdgcn_s_barrier();

    for (int kt = 0; kt < NT; ++kt) {
        char* rb = smb + (kt & 1) * 65536;
        const char* Ab = rb + (wm * 8) * 2048;
        const char* Bb = rb + 32768 + (wn * 4) * 2048;
        bf16x8 a0[4], a1[4], bv[4];

        // ---- phase 0: ss=0, m-frags 0..3 ----
#pragma unroll
        for (int i = 0; i < 4; ++i) {
            a0[i] = *(const bf16x8*)(Ab + i * 2048 + fr * 64 + sw);
            bv[i] = *(const bf16x8*)(Bb + i * 2048 + fr * 64 + sw);
        }
        __builtin_amdgcn_s_barrier();
        __builtin_amdgcn_s_setprio(1);
#pragma unroll
        for (int i = 0; i < 4; ++i)
#pragma unroll
            for (int j = 0; j < 4; ++j)
                MFMA16(acc[i][j], a0[i], bv[j]);
        __builtin_amdgcn_s_setprio(0);
        __builtin_amdgcn_s_barrier();

        // ---- phase 1: ss=0, m-frags 4..7 ----
#pragma unroll
        for (int i = 0; i < 4; ++i)
            a1[i] = *(const bf16x8*)(Ab + (4 + i) * 2048 + fr * 64 + sw);
        __builtin_amdgcn_s_barrier();
        __builtin_amdgcn_s_setprio(1);
#pragma unroll
        for (int i = 0; i < 4; ++i)
#pragma unroll
            for (int j = 0; j < 4; ++j)
                MFMA16(acc[4 + i][j], a1[i], bv[j]);
        __builtin_amdgcn_s_setprio(0);
        __builtin_amdgcn_s_barrier();

        // ---- phase 2: ss=1, m-frags 0..3 ----
#pragma unroll
        for (int i = 0; i < 4; ++i) {
            a0[i] = *(const bf16x8*)(Ab + i * 2048 + 1024 + fr * 64 + sw);
            bv[i] = *(const bf16x8*)(Bb + i * 2048 + 1024 + fr * 64 + sw);
        }
        __builtin_amdgcn_s_barrier();
        __builtin_amdgcn_s_setprio(1);
#pragma unroll
        for (int i = 0; i < 4; ++i)
#pragma unroll
            for (int j = 0; j < 4; ++j)
                MFMA16(acc[i][j], a0[i], bv[j]);
        __builtin_amdgcn_s_setprio(0);
        __builtin_amdgcn_s_barrier();

        // ---- phase 3: ss=1, m-frags 4..7 ----
#pragma unroll
        for (int i = 0; i < 4; ++i)
            a1[i] = *(const bf16x8*)(Ab + (4 + i) * 2048 + 1024 + fr * 64 + sw);
        __builtin_amdgcn_s_barrier();
        __builtin_amdgcn_s_setprio(1);
#pragma unroll
        for (int i = 0; i < 4; ++i)
#pragma unroll
            for (int j = 0; j < 4; ++j)
                MFMA16(acc[4 + i][j], a1[i], bv[j]);
        __builtin_amdgcn_s_setprio(0);
        __builtin_amdgcn_s_barrier();   // all waves done reading rb

        // ---- tail: prefetch kt+2 into rb, counted wait ----
        __builtin_amdgcn_sched_barrier(0);
        if (kt + 2 < NT) {
            stage_tile256(A, Bt, rb, m0, n0, K, (kt + 2) * 64,
                          wave, ldrow, gkoff);
            asm volatile("s_waitcnt vmcnt(8)" ::: "memory");
        } else if (kt + 1 < NT) {
            asm volatile("s_waitcnt vmcnt(0)" ::: "memory");
        }
        __builtin_amdgcn_s_barrier();
    }

    // ---- epilogue: 2 passes of 128 rows via LDS (stride 264 bf16), U2 out ----
    const int col_l = lane & 15;
    const int row_l = (lane >> 4) * 4;
    __hip_bfloat16* smC = (__hip_bfloat16*)smb;
    const int chunk = tid & 31;
    const int rbase = tid >> 5;
#pragma unroll
    for (int p = 0; p < 2; ++p) {
        __syncthreads();
        if (wm == p) {
#pragma unroll
            for (int i = 0; i < 8; ++i)
#pragma unroll
                for (int j = 0; j < 4; ++j)
#pragma unroll
                    for (int r = 0; r < 4; ++r)
                        smC[(i * 16 + row_l + r) * 264 + wn * 64 + j * 16 + col_l] =
                            __float2bfloat16(acc[i][j][r]);
        }
        __syncthreads();
#pragma unroll
        for (int it = 0; it < 8; ++it) {
            const int rr = it * 16 + rbase;
            bf16x8 v = *(const bf16x8*)(smC + rr * 264 + chunk * 8);
            const long gr  = m0 + p * 128 + rr;
            const long gc0 = n0 + chunk * 8;
            const int bI  = (int)(gr >> 10);
            const int t   = (int)(gr & 1023);
            const int dir = (int)(gc0 >> 10);
            const int hg  = ((int)gc0 >> 8) & 3;
            const int beta = bI * 8 + dir * 4 + hg;
            const long base = ((long)beta * 1024 + t) * 256 + ((int)gc0 & 255);
            *(bf16x8*)(C + base) = v;
        }
    }
}

// ---------------------------------------------------------------------------
// SRU scan, producer-consumer (harness-verified kernel; reads U at ~HBM
// ceiling already).
#define SCAN_S 64
#define SCAN_NB (T_DIM / SCAN_S)   // 16
#define GRP 16

__device__ __forceinline__ float scan_step(
    uint2 u, float c, float nvf, float nvr, float nbf, float nbr,
    __hip_bfloat16* hq)
{
    float u0, u1, u2, u3;
    unsigned a0 = u.x << 16, a1 = u.x & 0xffff0000u;
    unsigned a2 = u.y << 16, a3 = u.y & 0xffff0000u;
    __builtin_memcpy(&u0, &a0, 4); __builtin_memcpy(&u1, &a1, 4);
    __builtin_memcpy(&u2, &a2, 4); __builtin_memcpy(&u3, &a3, 4);
    const float nf0 = __builtin_fmaf(-LOG2E_F, u1, nbf);
    const float nr0 = __builtin_fmaf(-LOG2E_F, u2, nbr);
    const float ef = __builtin_amdgcn_exp2f(__builtin_fmaf(nvf, c, nf0));
    const float er = __builtin_amdgcn_exp2f(__builtin_fmaf(nvr, c, nr0));
    const float f  = __builtin_amdgcn_rcpf(1.0f + ef);
    const float r  = __builtin_amdgcn_rcpf(1.0f + er);
    const float c2 = __builtin_fmaf(f, c - u0, u0);
    const float hv = __builtin_fmaf(r, c2 - u3, u3);
    *hq = __float2bfloat16(hv);
    return c2;
}

__global__ __launch_bounds__(256) void sru_scan(
    const __hip_bfloat16* __restrict__ U2,
    const float* __restrict__ wc,    // (2,2,H)
    const float* __restrict__ bias,  // (2,2,H)
    __hip_bfloat16* __restrict__ hout)
{
    __shared__ __align__(16) char lds[2 * SCAN_S * 512];   // 65536 B
    const int tid  = threadIdx.x;
    const int wave = tid >> 6;
    const int lane = tid & 63;
    const int beta = blockIdx.x;
    const int b    = beta >> 3;
    const int dir  = (beta >> 2) & 1;
    const int hg   = beta & 3;
    const int h    = hg * 64 + lane;

    const char* gslice = (const char*)U2 + (size_t)beta * (1024 * 512);

    const float nvf = -LOG2E_F * wc[(dir * 2 + 0) * H_DIM + h];
    const float nvr = -LOG2E_F * wc[(dir * 2 + 1) * H_DIM + h];
    const float nbf = -LOG2E_F * bias[(dir * 2 + 0) * H_DIM + h];
    const float nbr = -LOG2E_F * bias[(dir * 2 + 1) * H_DIM + h];
    __hip_bfloat16* hp = hout + ((long)(b * 1024 + (dir ? 1023 : 0))) * 512 + dir * 256 + h;
    const long hstep = dir ? -512L : 512L;
    float c = 0.0f;

    const int plane = lane & 31;

    if (wave > 0) {
        for (int p = wave - 1; p < SCAN_S / 2; p += 3) {
            const int sl = 2 * p + (lane >> 5);
            const int t  = dir ? (1023 - sl) : sl;
            gload_lds16(gslice + (size_t)t * 512 + plane * 16, lds + p * 1024);
        }
    }
    __syncthreads();

    for (int bat = 0; bat < SCAN_NB; ++bat) {
        if (wave > 0) {
            if (bat + 1 < SCAN_NB) {
                char* halfN = lds + ((bat + 1) & 1) * (SCAN_S * 512);
                const int tb = (bat + 1) * SCAN_S;
                for (int p = wave - 1; p < SCAN_S / 2; p += 3) {
                    const int sl = tb + 2 * p + (lane >> 5);
                    const int t  = dir ? (1023 - sl) : sl;
                    gload_lds16(gslice + (size_t)t * 512 + plane * 16,
                                halfN + p * 1024);
                }
            }
        } else {
            const char* half = lds + (bat & 1) * (SCAN_S * 512);
            __hip_bfloat16* hq = hp + (long)(bat * SCAN_S) * hstep;
            uint2 qa[GRP], qb[GRP];
#pragma unroll
            for (int j = 0; j < GRP; ++j)
                qa[j] = *(const uint2*)(half + (0 * GRP + j) * 512 + (lane << 3));
#pragma unroll
            for (int j = 0; j < GRP; ++j)
                qb[j] = *(const uint2*)(half + (1 * GRP + j) * 512 + (lane << 3));
#pragma unroll
            for (int j = 0; j < GRP; ++j)
                c = scan_step(qa[j], c, nvf, nvr, nbf, nbr, hq + (long)j * hstep);
#pragma unroll
            for (int j = 0; j < GRP; ++j)
                qa[j] = *(const uint2*)(half + (2 * GRP + j) * 512 + (lane << 3));
#pragma unroll
            for (int j = 0; j < GRP; ++j)
                c = scan_step(qb[j], c, nvf, nvr, nbf, nbr, hq + (long)(GRP + j) * hstep);
#pragma unroll
            for (int j = 0; j < GRP; ++j)
                qb[j] = *(const uint2*)(half + (3 * GRP + j) * 512 + (lane << 3));
#pragma unroll
            for (int j = 0; j < GRP; ++j)
                c = scan_step(qa[j], c, nvf, nvr, nbf, nbr, hq + (long)(2 * GRP + j) * hstep);
#pragma unroll
            for (int j = 0; j < GRP; ++j)
                c = scan_step(qb[j], c, nvf, nvr, nbf, nbr, hq + (long)(3 * GRP + j) * hstep);
        }
        __syncthreads();
    }
}

// ---------------------------------------------------------------------------
// FUSED fc GEMM + logits + log_softmax (round-6 harness-verified kernel).
#define FL_BUF 49152             // per-kt staging: A 16384 + B 32768
#define FL_LP  98304             // lpwb region: 32 x 528 = 16896
#define FL_SCR 115200            // logits scratch: 128 x 36 f32 = 18432
#define FL_TOT 133632

__global__ __launch_bounds__(512, 1) void fc_logits(
    const __hip_bfloat16* __restrict__ A,     // h1b (32768, 512)
    const __hip_bfloat16* __restrict__ Bw,    // fc1wb (256, 512)
    const float* __restrict__ fcb,            // fc1_b (256,)
    const __hip_bfloat16* __restrict__ lpwb,  // (32,256) bf16, padded
    const float* __restrict__ lpb,            // (21,)
    float* __restrict__ out)                  // (32768, 21) f32
{
    __shared__ __align__(16) char lds[FL_TOT];
    const int tid  = threadIdx.x;
    const int lane = tid & 63;
    const int wave = tid >> 6;    // 0..7
    const int wm   = wave & 1;    // row half (64)
    const int wn   = wave >> 1;   // col quarter (64)
    const long m0  = (long)blockIdx.x * 128;

    const int ldrow = lane >> 2;
    const int ldq   = lane & 3;
    const int gq    = ldq ^ ((ldrow >> 1) & 3);
    const int gkoff = gq * 8;

    const int fr = lane & 15;
    const int kq = lane >> 4;
    const int sw = (kq ^ ((fr >> 1) & 3)) * 16;

    // stage lpwb (16 KB) once at 528-stride (vector loads + ds writes)
    for (int idx = tid; idx < 1024; idx += 512) {
        const int rw = idx >> 5, sl = idx & 31;
        *(bf16x8*)(lds + FL_LP + rw * 528 + sl * 16) =
            *(const bf16x8*)(lpwb + rw * 256 + sl * 8);
    }
    __builtin_amdgcn_sched_barrier(0);

    // ---- phase 1: fc GEMM, K=512, NT=8, dbuf, counted vmcnt(6) ----
    f32x4 acc[4][4] = {};

#define STAGE_FL(BUF, KB)                                                   \
    do {                                                                    \
        _Pragma("unroll")                                                   \
        for (int i2 = 0; i2 < 6; ++i2) {                                    \
            const int sg = wave * 6 + i2;  /* 0..47 */                      \
            if (sg < 16) {         /* A: 8 rc x 2 kh */                     \
                const int rc = sg >> 1, kh = sg & 1;                        \
                gload_lds16(A + (m0 + rc * 16 + ldrow) * 512L +             \
                                (KB) + kh * 32 + gkoff,                     \
                            (BUF) + rc * 2048 + kh * 1024);                 \
            } else {               /* B: 16 rc x 2 kh */                    \
                const int t2 = sg - 16, rc = t2 >> 1, kh = t2 & 1;          \
                gload_lds16(Bw + (rc * 16 + ldrow) * 512L +                 \
                                 (KB) + kh * 32 + gkoff,                    \
                            (BUF) + 16384 + rc * 2048 + kh * 1024);         \
            }                                                               \
        }                                                                   \
    } while (0)

    STAGE_FL(lds, 0);

    for (int kt = 0; kt < 8; ++kt) {
        char* cur = lds + (kt & 1) * FL_BUF;
        char* nxt = lds + ((kt + 1) & 1) * FL_BUF;
        __builtin_amdgcn_sched_barrier(0);
        if (kt + 1 < 8) {
            STAGE_FL(nxt, (kt + 1) * 64);
            __builtin_amdgcn_sched_barrier(0);
            asm volatile("s_waitcnt vmcnt(6)" ::: "memory");
        } else {
            asm volatile("s_waitcnt vmcnt(0)" ::: "memory");
        }
        __builtin_amdgcn_s_barrier();

#pragma unroll
        for (int ss = 0; ss < 2; ++ss) {
            bf16x8 af[4], bfv[4];
#pragma unroll
            for (int i = 0; i < 4; ++i) {
                af[i]  = *(const bf16x8*)(cur + (wm * 4 + i) * 2048 + ss * 1024 + fr * 64 + sw);
                bfv[i] = *(const bf16x8*)(cur + 16384 + (wn * 4 + i) * 2048 + ss * 1024 + fr * 64 + sw);
            }
            __builtin_amdgcn_s_setprio(1);
#pragma unroll
            for (int i = 0; i < 4; ++i)
#pragma unroll
                for (int j = 0; j < 4; ++j)
                    MFMA16(acc[i][j], af[i], bfv[j]);
            __builtin_amdgcn_s_setprio(0);
        }
        __builtin_amdgcn_s_barrier();   // reads of cur complete
    }
#undef STAGE_FL

    // ---- dump fc tile to LDS as bf16, stride 260 elems (+bias) ----
    const int col_l = lane & 15;
    const int row_l = (lane >> 4) * 4;
    __hip_bfloat16* fcX = (__hip_bfloat16*)lds;
#pragma unroll
    for (int j = 0; j < 4; ++j) {
        const int gc = wn * 64 + j * 16 + col_l;
        const float bv = fcb[gc];
#pragma unroll
        for (int i = 0; i < 4; ++i)
#pragma unroll
            for (int r = 0; r < 4; ++r)
                fcX[(wm * 64 + i * 16 + row_l + r) * 260 + gc] =
                    __float2bfloat16(acc[i][j][r] + bv);
    }
    __syncthreads();

    // ---- phase 2: logits MFMA over K=256 from LDS ----
    const int rb = wave * 16;     // 16 rows per wave
    f32x4 acc2[2] = {};
#pragma unroll
    for (int kc = 0; kc < 8; ++kc) {
        bf16x8 afx = *(const bf16x8*)(lds + (rb + fr) * 520 + kc * 64 + kq * 16);
        bf16x8 b0  = *(const bf16x8*)(lds + FL_LP + fr * 528 + kc * 64 + kq * 16);
        bf16x8 b1  = *(const bf16x8*)(lds + FL_LP + (16 + fr) * 528 + kc * 64 + kq * 16);
        MFMA16(acc2[0], afx, b0);
        MFMA16(acc2[1], afx, b1);
    }

    float* smL = (float*)(lds + FL_SCR);   // stride 36 f32
#pragma unroll
    for (int j = 0; j < 2; ++j) {
        const int gc = j * 16 + col_l;
        const float bv = (gc < AA_DIM) ? lpb[gc] : 0.0f;
#pragma unroll
        for (int r = 0; r < 4; ++r)
            smL[(rb + row_l + r) * 36 + gc] = acc2[j][r] + bv;
    }
    __syncthreads();

    if (tid < 128) {
        const float* rowp = smL + tid * 36;
        float m = rowp[0];
#pragma unroll
        for (int a = 1; a < AA_DIM; ++a) m = fmaxf(m, rowp[a]);
        float s = 0.0f;
#pragma unroll
        for (int a = 0; a < AA_DIM; ++a) s += __expf(rowp[a] - m);
        const float lse = __logf(s) + m;
        float* op = out + (m0 + tid) * AA_DIM;
#pragma unroll
        for (int a = 0; a < AA_DIM; ++a) op[a] = rowp[a] - lse;
    }
}

// ---------------------------------------------------------------------------
extern "C" void kernel_launch(void* const* d_in, const int* in_sizes, int n_in,
                              void* d_out, int out_size, void* d_ws, size_t ws_size,
                              hipStream_t stream)
{
    const float* x     = (const float*)d_in[0];
    const float* w_l0  = (const float*)d_in[2];
    const float* wc_l0 = (const float*)d_in[3];
    const float* b_l0  = (const float*)d_in[4];
    const float* w_l1  = (const float*)d_in[5];
    const float* wc_l1 = (const float*)d_in[6];
    const float* b_l1  = (const float*)d_in[7];
    const float* fc1_w = (const float*)d_in[8];
    const float* fc1_b = (const float*)d_in[9];
    const float* lp_w  = (const float*)d_in[10];
    const float* lp_b  = (const float*)d_in[11];
    float* out = (float*)d_out;

    char* ws = (char*)d_ws;
    __hip_bfloat16* U      = (__hip_bfloat16*)(ws);              // 134,217,728 B (U2 layout)
    __hip_bfloat16* h0b    = (__hip_bfloat16*)(ws + 134217728);  //  33,554,432
    __hip_bfloat16* h1b    = (__hip_bfloat16*)(ws + 167772160);  //  33,554,432
    __hip_bfloat16* xb     = (__hip_bfloat16*)(ws + 201326592);  //  16,777,216
    __hip_bfloat16* w0t    = (__hip_bfloat16*)(ws + 218103808);  //  (2048,256)
    __hip_bfloat16* w1t    = (__hip_bfloat16*)(ws + 219152384);  //  (2048,512)
    __hip_bfloat16* fc1wb  = (__hip_bfloat16*)(ws + 221249536);  //  (256,512)
    __hip_bfloat16* lpwb   = (__hip_bfloat16*)(ws + 221511680);  //  (32,256)

    cvt_all<<<(CVT_TOT + 255) / 256, 256, 0, stream>>>(
        x, w_l0, w_l1, fc1_w, lp_w, xb, w0t, w1t, fc1wb, lpwb);

    // U-GEMMs: 256^2 tiles, MB=128 x NB=8 -> 1024 blocks, nbShift=3
    gemm256_u2<<<1024, 512, 0, stream>>>(xb, w0t, U, DIN_DIM, 3);
    sru_scan<<<256, 256, 0, stream>>>(U, wc_l0, b_l0, h0b);
    gemm256_u2<<<1024, 512, 0, stream>>>(h0b, w1t, U, 512, 3);
    sru_scan<<<256, 256, 0, stream>>>(U, wc_l1, b_l1, h1b);

    // fused fc GEMM + logits + log_softmax: 256 blocks (1/CU), 8 waves
    fc_logits<<<256, 512, 0, stream>>>(h1b, fc1wb, fc1_b, lpwb, lp_b, out);
}